// Round 5
// baseline (446.837 us; speedup 1.0000x reference)
//
#include <hip/hip_runtime.h>
#include <math.h>

typedef _Float16 f16x8 __attribute__((ext_vector_type(8)));
typedef float f32x4 __attribute__((ext_vector_type(4)));
typedef unsigned short ushort_t;

constexpr int HWp = 2304;
constexpr float EPS = 1e-5f;

// ws layout (bytes):
//   0       w1h (65536)   | 65536  w1l | 131072 w2h | 196608 w2l
//   262144  qkBh (4096)   | 266240 qkBl (4096)
//   270336  qb2 (64)      | 270400 peG (3072)
//   273664  xp  (4608*3072*8 = 113246208)
constexpr size_t XP_OFF    = 273664;
constexpr size_t XP_BYTES  = (size_t)4608 * 3072 * 8;
constexpr size_t WS_NEEDED = XP_OFF + XP_BYTES;

// swizzled fp16 index into a [48][128] tile with 256B rows:
__device__ __forceinline__ int sidx(int row, int c) {
    return ((row << 8) + ((c << 1) ^ ((row & 7) << 4))) >> 1;
}

__device__ __forceinline__ unsigned packsplit(float v) {
    _Float16 h = (_Float16)v;
    _Float16 lo = (_Float16)(v - (float)h);
    return (unsigned)__builtin_bit_cast(ushort_t, h) |
           ((unsigned)__builtin_bit_cast(ushort_t, lo) << 16);
}

// ---------------- prep: weights -> split fp16, fold Q+scale, PE table ----------------
__global__ void ltae_prep(const float* __restrict__ w_in0, const float* __restrict__ w_in1,
                          const float* __restrict__ Qm, const float* __restrict__ w_k,
                          const float* __restrict__ b_k, const int* __restrict__ bpos,
                          _Float16* __restrict__ w1h, _Float16* __restrict__ w1l,
                          _Float16* __restrict__ w2h, _Float16* __restrict__ w2l,
                          _Float16* __restrict__ qkBh, _Float16* __restrict__ qkBl,
                          float* __restrict__ qb2G, float* __restrict__ peG) {
    int i = blockIdx.x * 256 + threadIdx.x;
    if (i < 32768) {
        float v = w_in0[i];
        _Float16 h = (_Float16)v;
        w1h[i] = h; w1l[i] = (_Float16)(v - (float)h);
    } else if (i < 65536) {
        int j = i - 32768;
        float v = w_in1[j];
        _Float16 h = (_Float16)v;
        w2h[j] = h; w2l[j] = (_Float16)(v - (float)h);
    } else if (i < 67584) {
        int j = i - 65536; int h = j >> 7, k = j & 127;
        float s = 0.f;
        #pragma unroll
        for (int dk = 0; dk < 4; dk++) s = fmaf(Qm[h * 4 + dk], w_k[(h * 4 + dk) * 128 + k], s);
        s *= 0.5f;
        _Float16 hi = (_Float16)s;
        int ks = k >> 5, lg = (k >> 3) & 3, jj = k & 7;
        int pos = ((ks * 4 + lg) * 16 + h) * 8 + jj;
        qkBh[pos] = hi; qkBl[pos] = (_Float16)(s - (float)hi);
    } else if (i < 67600) {
        int h = i - 67584;
        float s = 0.f;
        #pragma unroll
        for (int dk = 0; dk < 4; dk++) s = fmaf(Qm[h * 4 + dk], b_k[h * 4 + dk], s);
        qb2G[h] = 0.5f * s;
    } else if (i < 68368) {
        int j = i - 67600;                 // b*192 + t*8 + d
        int bb = j / 192, r = j - bb * 192;
        int t = r >> 3, d = r & 7;
        const float dens[4] = {1.0f, 5.623413251903491f, 31.622776601683793f, 177.82794100389228f};
        float ang = (float)bpos[bb * 24 + t] / dens[d >> 1];
        peG[j] = (d & 1) ? cosf(ang) : sinf(ang);
    }
}

// ---------------- pack: x (B,T,C,H,W) -> pair-packed split-fp16, coalesced ----------------
__global__ __launch_bounds__(256) void ltae_pack(const float* __restrict__ x,
                                                 uint2* __restrict__ xp) {
    __shared__ unsigned tile[64][129];
    const int bid = blockIdx.x;            // 4 b * 24 t * 36 pixgroups = 3456
    const int pg = bid % 36;
    const int rem = bid / 36;
    const int t = rem % 24;
    const int b = rem / 24;
    const int pix0 = pg * 64;
    const float* src = x + ((size_t)((b * 24 + t) * 128)) * HWp + pix0;

    #pragma unroll
    for (int k = 0; k < 8; k++) {
        int i = threadIdx.x + (k << 8);    // 0..2047
        int c = i >> 4, p4 = (i & 15) << 2;
        float4 v = *(const float4*)(src + (size_t)c * HWp + p4);
        tile[p4 + 0][c] = packsplit(v.x);
        tile[p4 + 1][c] = packsplit(v.y);
        tile[p4 + 2][c] = packsplit(v.z);
        tile[p4 + 3][c] = packsplit(v.w);
    }
    __syncthreads();
    const int P0 = b * 1152 + (pix0 >> 1);
    #pragma unroll
    for (int k = 0; k < 8; k++) {
        int i = threadIdx.x + (k << 8);    // 0..2047
        int pr = i >> 6, c = (i & 63) << 1;
        uint4 v;
        v.x = tile[2 * pr][c];     v.y = tile[2 * pr + 1][c];
        v.z = tile[2 * pr][c + 1]; v.w = tile[2 * pr + 1][c + 1];
        *(uint4*)(xp + ((size_t)(P0 + pr) * 24 + t) * 128 + c) = v;
    }
}

// ---------------- main fused kernel: 2 pixels per block, 3 blocks/CU ----------------
__global__ __launch_bounds__(256, 3) void ltae_main(
    const float* __restrict__ x, const uint2* __restrict__ xp, const int packed,
    const float* __restrict__ b_in0, const float* __restrict__ g_in0, const float* __restrict__ be_in0,
    const float* __restrict__ b_in1, const float* __restrict__ g_in1, const float* __restrict__ be_in1,
    const float* __restrict__ g_innorm, const float* __restrict__ b_innorm,
    const float* __restrict__ w_m0, const float* __restrict__ b_m0,
    const float* __restrict__ g_m0, const float* __restrict__ be_m0,
    const float* __restrict__ w_m1, const float* __restrict__ b_m1,
    const float* __restrict__ g_m1, const float* __restrict__ be_m1,
    const float* __restrict__ g_out, const float* __restrict__ b_out,
    const _Float16* __restrict__ w1h, const _Float16* __restrict__ w1l,
    const _Float16* __restrict__ w2h, const _Float16* __restrict__ w2l,
    const _Float16* __restrict__ qkBh, const _Float16* __restrict__ qkBl,
    const float* __restrict__ qb2G, const float* __restrict__ peG,
    float* __restrict__ out)
{
    __shared__ __align__(16) _Float16 Ah[48 * 128], Al[48 * 128];  // tokens, later xs2 hi/lo
    __shared__ __align__(16) _Float16 Hh[48 * 128], Hl[48 * 128];  // h1 half-tile hi/lo
    __shared__ float peS[24][8];
    __shared__ float muS[2][16], rsS[2][16];
    __shared__ float gS[128], bnS[128];
    __shared__ float2 partS[192];

    float* scP = (float*)Hh;          // [2][16][24] overlays H after GEMMs
    float* ovP = scP + 768;           // [2][128]
    float* mmP = ovP + 256;           // [2][256]
    float* ysP = ovP;

    const int tid = threadIdx.x;
    const int bid = blockIdx.x;
    const int sb  = (bid & 7) * 576 + (bid >> 3);   // bijective XCD swizzle (4608 % 8 == 0)
    const int b   = sb / 1152;
    const int pixbase = (sb - b * 1152) * 2;

    // ---- Phase 0: PE table, gamma cache, gather tokens -> Ah/Al ----
    if (tid < 192) peS[tid >> 3][tid & 7] = peG[b * 192 + tid];
    if (tid < 128) { gS[tid] = g_innorm[tid]; bnS[tid] = b_innorm[tid]; }
    if (packed) {
        ushort_t* AhU = (ushort_t*)Ah;
        ushort_t* AlU = (ushort_t*)Al;
        const uint2* xq = xp + (size_t)sb * 3072;
        #pragma unroll
        for (int k = 0; k < 6; k++) {
            int i = tid + (k << 8);            // 0..1535
            int t = i >> 6, c2 = (i & 63) << 1;
            uint4 v = *(const uint4*)(xq + t * 128 + c2);
            int i0 = sidx(t, c2);              // c2 even -> i0, i0+1 adjacent
            int i1 = sidx(24 + t, c2);
            *(ushort2*)(AhU + i0) = ushort2{(ushort_t)(v.x & 0xffff), (ushort_t)(v.z & 0xffff)};
            *(ushort2*)(AlU + i0) = ushort2{(ushort_t)(v.x >> 16),    (ushort_t)(v.z >> 16)};
            *(ushort2*)(AhU + i1) = ushort2{(ushort_t)(v.y & 0xffff), (ushort_t)(v.w & 0xffff)};
            *(ushort2*)(AlU + i1) = ushort2{(ushort_t)(v.y >> 16),    (ushort_t)(v.w >> 16)};
        }
    } else {
        for (int i = tid; i < 24 * 128; i += 256) {
            int t = i >> 7, c = i & 127;
            const float* gp = x + ((size_t)((b * 24 + t) * 128 + c)) * HWp + pixbase;
            float2 v = *(const float2*)gp;
            _Float16 h0 = (_Float16)v.x;
            _Float16 h1 = (_Float16)v.y;
            int i0 = sidx(t, c), i1 = sidx(24 + t, c);
            Ah[i0] = h0; Al[i0] = (_Float16)(v.x - (float)h0);
            Ah[i1] = h1; Al[i1] = (_Float16)(v.y - (float)h1);
        }
    }
    __syncthreads();

    const int w  = tid >> 6;
    const int l  = tid & 63;
    const int lr = l & 15;
    const int lg = l >> 4;

    // ---- GEMM1 (two N-halves) + GEMM2 (partial-accumulate over K-halves) ----
    f32x4 g2acc[3][2];
    #pragma unroll
    for (int m = 0; m < 3; m++)
        #pragma unroll
        for (int nt = 0; nt < 2; nt++) g2acc[m][nt] = f32x4{0.f, 0.f, 0.f, 0.f};

    #pragma unroll 1
    for (int half = 0; half < 2; half++) {
        f16x8 bh[2][4], bl[2][4];
        float gg[2], bb[2], bi[2];
        #pragma unroll
        for (int nt = 0; nt < 2; nt++) {
            int n = half * 128 + w * 32 + nt * 16 + lr;
            #pragma unroll
            for (int ks = 0; ks < 4; ks++) {
                bh[nt][ks] = *(const f16x8*)(w1h + n * 128 + ks * 32 + lg * 8);
                bl[nt][ks] = *(const f16x8*)(w1l + n * 128 + ks * 32 + lg * 8);
            }
            gg[nt] = g_in0[n]; bb[nt] = be_in0[n]; bi[nt] = b_in0[n];
        }
        f32x4 acc[3][2];
        #pragma unroll
        for (int m = 0; m < 3; m++)
            #pragma unroll
            for (int nt = 0; nt < 2; nt++) acc[m][nt] = f32x4{0.f, 0.f, 0.f, 0.f};
        #pragma unroll
        for (int m = 0; m < 3; m++) {
            #pragma unroll
            for (int ks = 0; ks < 4; ks++) {
                f16x8 ah = *(const f16x8*)&Ah[sidx(m * 16 + lr, ks * 32 + lg * 8)];
                f16x8 al = *(const f16x8*)&Al[sidx(m * 16 + lr, ks * 32 + lg * 8)];
                #pragma unroll
                for (int nt = 0; nt < 2; nt++) {
                    acc[m][nt] = __builtin_amdgcn_mfma_f32_16x16x32_f16(ah, bl[nt][ks], acc[m][nt], 0, 0, 0);
                    acc[m][nt] = __builtin_amdgcn_mfma_f32_16x16x32_f16(al, bh[nt][ks], acc[m][nt], 0, 0, 0);
                    acc[m][nt] = __builtin_amdgcn_mfma_f32_16x16x32_f16(ah, bh[nt][ks], acc[m][nt], 0, 0, 0);
                }
            }
        }
        float ps[3][4], ps2[3][4];
        #pragma unroll
        for (int m = 0; m < 3; m++) {
            #pragma unroll
            for (int r = 0; r < 4; r++) {
                float v0 = acc[m][0][r] + bi[0], v1 = acc[m][1][r] + bi[1];
                float s = v0 + v1, s2 = v0 * v0 + v1 * v1;
                #pragma unroll
                for (int mk = 1; mk <= 8; mk <<= 1) { s += __shfl_xor(s, mk); s2 += __shfl_xor(s2, mk); }
                ps[m][r] = s; ps2[m][r] = s2;
            }
        }
        if (lr == 0) {
            #pragma unroll
            for (int m = 0; m < 3; m++)
                #pragma unroll
                for (int r = 0; r < 4; r++)
                    partS[w * 48 + m * 16 + lg * 4 + r] = make_float2(ps[m][r], ps2[m][r]);
        }
        __syncthreads();
        #pragma unroll
        for (int m = 0; m < 3; m++) {
            #pragma unroll
            for (int r = 0; r < 4; r++) {
                float2 q = partS[(w ^ 1) * 48 + m * 16 + lg * 4 + r];
                float st = ps[m][r] + q.x, s2t = ps2[m][r] + q.y;
                float mu = st * (1.f / 64.f);
                float rs = rsqrtf(s2t * (1.f / 64.f) - mu * mu + EPS);
                int row = m * 16 + lg * 4 + r;
                #pragma unroll
                for (int nt = 0; nt < 2; nt++) {
                    float v = acc[m][nt][r] + bi[nt];
                    float hv = fmaxf(fmaf((v - mu) * rs, gg[nt], bb[nt]), 0.f);
                    _Float16 h16 = (_Float16)hv;
                    int ii = sidx(row, w * 32 + nt * 16 + lr);
                    Hh[ii] = h16;
                    Hl[ii] = (_Float16)(hv - (float)h16);
                }
            }
        }
        __syncthreads();

        f16x8 b2h[2][4], b2l[2][4];
        #pragma unroll
        for (int nt = 0; nt < 2; nt++) {
            int n = w * 32 + nt * 16 + lr;
            #pragma unroll
            for (int ks = 0; ks < 4; ks++) {
                b2h[nt][ks] = *(const f16x8*)(w2h + n * 256 + half * 128 + ks * 32 + lg * 8);
                b2l[nt][ks] = *(const f16x8*)(w2l + n * 256 + half * 128 + ks * 32 + lg * 8);
            }
        }
        #pragma unroll
        for (int m = 0; m < 3; m++) {
            #pragma unroll
            for (int ks = 0; ks < 4; ks++) {
                f16x8 ah = *(const f16x8*)&Hh[sidx(m * 16 + lr, ks * 32 + lg * 8)];
                f16x8 al = *(const f16x8*)&Hl[sidx(m * 16 + lr, ks * 32 + lg * 8)];
                #pragma unroll
                for (int nt = 0; nt < 2; nt++) {
                    g2acc[m][nt] = __builtin_amdgcn_mfma_f32_16x16x32_f16(ah, b2l[nt][ks], g2acc[m][nt], 0, 0, 0);
                    g2acc[m][nt] = __builtin_amdgcn_mfma_f32_16x16x32_f16(al, b2h[nt][ks], g2acc[m][nt], 0, 0, 0);
                    g2acc[m][nt] = __builtin_amdgcn_mfma_f32_16x16x32_f16(ah, b2h[nt][ks], g2acc[m][nt], 0, 0, 0);
                }
            }
        }
        __syncthreads();
    }

    // ---- GEMM2 epilogue: bias + GN(4/32) + ReLU -> xs2 hi/lo (A region) ----
    {
        float gg2[2], bb2[2], bi2[2];
        #pragma unroll
        for (int nt = 0; nt < 2; nt++) {
            int n = w * 32 + nt * 16 + lr;
            gg2[nt] = g_in1[n]; bb2[nt] = be_in1[n]; bi2[nt] = b_in1[n];
        }
        #pragma unroll
        for (int m = 0; m < 3; m++) {
            #pragma unroll
            for (int r = 0; r < 4; r++) {
                float v0 = g2acc[m][0][r] + bi2[0], v1 = g2acc[m][1][r] + bi2[1];
                float s = v0 + v1, s2 = v0 * v0 + v1 * v1;
                #pragma unroll
                for (int mk = 1; mk <= 8; mk <<= 1) { s += __shfl_xor(s, mk); s2 += __shfl_xor(s2, mk); }
                float mu = s * (1.f / 32.f);
                float rs = rsqrtf(s2 * (1.f / 32.f) - mu * mu + EPS);
                int row = m * 16 + lg * 4 + r;
                float h0 = fmaxf(fmaf((v0 - mu) * rs, gg2[0], bb2[0]), 0.f);
                float h1v = fmaxf(fmaf((v1 - mu) * rs, gg2[1], bb2[1]), 0.f);
                _Float16 p0 = (_Float16)h0, p1 = (_Float16)h1v;
                int i0 = sidx(row, w * 32 + lr), i1 = sidx(row, w * 32 + 16 + lr);
                Ah[i0] = p0; Al[i0] = (_Float16)(h0 - (float)p0);
                Ah[i1] = p1; Al[i1] = (_Float16)(h1v - (float)p1);
            }
        }
    }
    __syncthreads();

    // ---- Phase 3: in_norm GN(16 over C,T) stats ----
    {
        const int p = w >> 1, hw = w & 1;
        int g = hw * 8 + (l >> 3), j = l & 7;
        float s = 0.f, s2 = 0.f;
        #pragma unroll
        for (int k = 0; k < 24; k++) {
            int e = j + 8 * k;
            int t = e >> 3, co = e & 7;
            int ii = sidx(p * 24 + t, g * 8 + co);
            float v = (float)Ah[ii] + (float)Al[ii];
            s += v; s2 += v * v;
        }
        s += __shfl_xor(s, 1);  s += __shfl_xor(s, 2);  s += __shfl_xor(s, 4);
        s2 += __shfl_xor(s2, 1); s2 += __shfl_xor(s2, 2); s2 += __shfl_xor(s2, 4);
        if (j == 0) {
            float mu = s * (1.f / 192.f);
            muS[p][g] = mu;
            rsS[p][g] = rsqrtf(s2 * (1.f / 192.f) - mu * mu + EPS);
        }
    }
    __syncthreads();
    for (int i = tid; i < 48 * 128; i += 256) {
        int row = i >> 7, c = i & 127;
        int p = row >= 24 ? 1 : 0;
        int t = row - p * 24;
        int ii = sidx(row, c);
        float v = (float)Ah[ii] + (float)Al[ii];
        v = (v - muS[p][c >> 3]) * rsS[p][c >> 3] * gS[c] + bnS[c] + peS[t][c & 7];
        _Float16 h16 = (_Float16)v;
        Ah[ii] = h16; Al[ii] = (_Float16)(v - (float)h16);
    }
    __syncthreads();

    // ---- Phase 4: scores via split-fp16 MFMA (waves 0..2) ----
    if (w < 3) {
        const int m = w;
        f16x8 qh[4], ql[4];
        #pragma unroll
        for (int ks = 0; ks < 4; ks++) {
            qh[ks] = *(const f16x8*)(qkBh + ((ks * 4 + lg) * 16 + lr) * 8);
            ql[ks] = *(const f16x8*)(qkBl + ((ks * 4 + lg) * 16 + lr) * 8);
        }
        f32x4 sacc = f32x4{0.f, 0.f, 0.f, 0.f};
        #pragma unroll
        for (int ks = 0; ks < 4; ks++) {
            f16x8 ah = *(const f16x8*)&Ah[sidx(m * 16 + lr, ks * 32 + lg * 8)];
            f16x8 al = *(const f16x8*)&Al[sidx(m * 16 + lr, ks * 32 + lg * 8)];
            sacc = __builtin_amdgcn_mfma_f32_16x16x32_f16(ah, ql[ks], sacc, 0, 0, 0);
            sacc = __builtin_amdgcn_mfma_f32_16x16x32_f16(al, qh[ks], sacc, 0, 0, 0);
            sacc = __builtin_amdgcn_mfma_f32_16x16x32_f16(ah, qh[ks], sacc, 0, 0, 0);
        }
        float qb = qb2G[lr];
        #pragma unroll
        for (int r = 0; r < 4; r++) {
            int row = m * 16 + lg * 4 + r;
            int p = row >= 24 ? 1 : 0;
            int t = row - p * 24;
            scP[(p * 16 + lr) * 24 + t] = sacc[r] + qb;
        }
    }
    __syncthreads();

    // ---- softmax ----
    {
        const int p = w >> 1;
        int h = (w & 1) * 8 + (l >> 3), j = l & 7;
        float* sp = scP + (p * 16 + h) * 24;
        float mx = -1e30f;
        #pragma unroll
        for (int k = 0; k < 3; k++) mx = fmaxf(mx, sp[j + 8 * k]);
        mx = fmaxf(mx, __shfl_xor(mx, 1));
        mx = fmaxf(mx, __shfl_xor(mx, 2));
        mx = fmaxf(mx, __shfl_xor(mx, 4));
        float ev[3], sum = 0.f;
        #pragma unroll
        for (int k = 0; k < 3; k++) { ev[k] = __expf(sp[j + 8 * k] - mx); sum += ev[k]; }
        sum += __shfl_xor(sum, 1);
        sum += __shfl_xor(sum, 2);
        sum += __shfl_xor(sum, 4);
        float inv = 1.f / sum;
        #pragma unroll
        for (int k = 0; k < 3; k++) sp[j + 8 * k] = ev[k] * inv;
    }

    // ---- Phase 5: o = a . v ----
    {
        const int p = w >> 1;
        int ch = (w & 1) * 64 + l;
        int h = ch >> 3;
        const float* sp = scP + (p * 16 + h) * 24;
        float s = 0.f;
        #pragma unroll
        for (int t = 0; t < 24; t++) {
            int ii = sidx(p * 24 + t, ch);
            s = fmaf(sp[t], (float)Ah[ii] + (float)Al[ii], s);
        }
        ovP[p * 128 + ch] = s;
    }
    __syncthreads();

    // ---- Phase 6: MLP layer 1 (128->256) + GN(4/64) + ReLU ----
    {
        const int o = tid;
        const float* wr = w_m0 + o * 128;
        float acc[2] = {0.f, 0.f};
        for (int c0 = 0; c0 < 128; c0 += 4) {
            float4 w4 = *(const float4*)(wr + c0);
            #pragma unroll
            for (int pp = 0; pp < 2; pp++) {
                float4 x4 = *(const float4*)(ovP + pp * 128 + c0);
                acc[pp] = fmaf(w4.x, x4.x, acc[pp]); acc[pp] = fmaf(w4.y, x4.y, acc[pp]);
                acc[pp] = fmaf(w4.z, x4.z, acc[pp]); acc[pp] = fmaf(w4.w, x4.w, acc[pp]);
            }
        }
        float bi = b_m0[o], gg = g_m0[o], bb = be_m0[o];
        #pragma unroll
        for (int pp = 0; pp < 2; pp++) {
            float v = acc[pp] + bi;
            float s = v, s2 = v * v;
            #pragma unroll
            for (int mk = 1; mk <= 32; mk <<= 1) { s += __shfl_xor(s, mk); s2 += __shfl_xor(s2, mk); }
            float mu = s * (1.f / 64.f);
            float rs = rsqrtf(s2 * (1.f / 64.f) - mu * mu + EPS);
            mmP[pp * 256 + o] = fmaxf(fmaf((v - mu) * rs, gg, bb), 0.f);
        }
    }
    __syncthreads();

    // ---- Phase 7: MLP layer 2 + GN(4/32) + ReLU + out_norm GN(16/8) ----
    {
        const int o = tid & 127, pp = tid >> 7;
        const float* wr = w_m1 + o * 256;
        float acc = 0.f;
        for (int c0 = 0; c0 < 256; c0 += 4) {
            float4 w4 = *(const float4*)(wr + c0);
            float4 x4 = *(const float4*)(mmP + pp * 256 + c0);
            acc = fmaf(w4.x, x4.x, acc); acc = fmaf(w4.y, x4.y, acc);
            acc = fmaf(w4.z, x4.z, acc); acc = fmaf(w4.w, x4.w, acc);
        }
        float v = acc + b_m1[o];
        float s = v, s2 = v * v;
        #pragma unroll
        for (int mk = 1; mk <= 16; mk <<= 1) { s += __shfl_xor(s, mk); s2 += __shfl_xor(s2, mk); }
        float mu = s * (1.f / 32.f);
        float rs = rsqrtf(s2 * (1.f / 32.f) - mu * mu + EPS);
        float v2 = fmaxf(fmaf((v - mu) * rs, g_m1[o], be_m1[o]), 0.f);
        float t1 = v2, t2 = v2 * v2;
        #pragma unroll
        for (int mk = 1; mk <= 4; mk <<= 1) { t1 += __shfl_xor(t1, mk); t2 += __shfl_xor(t2, mk); }
        float mu2 = t1 * (1.f / 8.f);
        float rs2 = rsqrtf(t2 * (1.f / 8.f) - mu2 * mu2 + EPS);
        ysP[pp * 128 + o] = fmaf((v2 - mu2) * rs2, g_out[o], b_out[o]);
    }
    __syncthreads();

    // ---- Phase 8: store ----
    if (tid < 128) {
        float2 y2;
        y2.x = ysP[0 * 128 + tid];
        y2.y = ysP[1 * 128 + tid];
        *(float2*)(out + ((size_t)(b * 128 + tid)) * HWp + pixbase) = y2;
    }
}

extern "C" void kernel_launch(void* const* d_in, const int* in_sizes, int n_in,
                              void* d_out, int out_size, void* d_ws, size_t ws_size,
                              hipStream_t stream) {
    const float* x        = (const float*)d_in[0];
    const int*   bpos     = (const int*)  d_in[1];
    const float* w_in0    = (const float*)d_in[2];
    const float* b_in0    = (const float*)d_in[3];
    const float* g_in0    = (const float*)d_in[4];
    const float* be_in0   = (const float*)d_in[5];
    const float* w_in1    = (const float*)d_in[6];
    const float* b_in1    = (const float*)d_in[7];
    const float* g_in1    = (const float*)d_in[8];
    const float* be_in1   = (const float*)d_in[9];
    const float* g_innorm = (const float*)d_in[10];
    const float* b_innorm = (const float*)d_in[11];
    const float* Qm       = (const float*)d_in[12];
    const float* w_k      = (const float*)d_in[13];
    const float* b_k      = (const float*)d_in[14];
    const float* w_m0     = (const float*)d_in[15];
    const float* b_m0     = (const float*)d_in[16];
    const float* g_m0     = (const float*)d_in[17];
    const float* be_m0    = (const float*)d_in[18];
    const float* w_m1     = (const float*)d_in[19];
    const float* b_m1     = (const float*)d_in[20];
    const float* g_m1     = (const float*)d_in[21];
    const float* be_m1    = (const float*)d_in[22];
    const float* g_out    = (const float*)d_in[23];
    const float* b_out    = (const float*)d_in[24];

    _Float16* w1h  = (_Float16*)d_ws;
    _Float16* w1l  = w1h + 32768;
    _Float16* w2h  = w1l + 32768;
    _Float16* w2l  = w2h + 32768;
    _Float16* qkBh = (_Float16*)((char*)d_ws + 262144);
    _Float16* qkBl = qkBh + 2048;
    float*    qb2G = (float*)((char*)d_ws + 270336);
    float*    peG  = (float*)((char*)d_ws + 270400);
    uint2*    xpG  = (uint2*)((char*)d_ws + XP_OFF);

    const int packed = (ws_size >= WS_NEEDED) ? 1 : 0;

    hipLaunchKernelGGL(ltae_prep, dim3(268), dim3(256), 0, stream,
                       w_in0, w_in1, Qm, w_k, b_k, bpos,
                       w1h, w1l, w2h, w2l, qkBh, qkBl, qb2G, peG);

    if (packed) {
        hipLaunchKernelGGL(ltae_pack, dim3(3456), dim3(256), 0, stream, x, xpG);
    }

    hipLaunchKernelGGL(ltae_main, dim3(4608), dim3(256), 0, stream,
                       x, xpG, packed,
                       b_in0, g_in0, be_in0,
                       b_in1, g_in1, be_in1,
                       g_innorm, b_innorm,
                       w_m0, b_m0, g_m0, be_m0,
                       w_m1, b_m1, g_m1, be_m1,
                       g_out, b_out,
                       w1h, w1l, w2h, w2l, qkBh, qkBl, qb2G, peG,
                       (float*)d_out);
}